// Round 3
// baseline (177.944 us; speedup 1.0000x reference)
//
#include <hip/hip_runtime.h>
#include <hip/hip_fp8.h>
#include <cstdint>

// ---------------------------------------------------------------------------
// DeepFM forward, MI355X (R15 = R14 fat tile + BK=128 dbuf counted-vmcnt).
//   R14 post-mortem: 4x8-frag tile made GEMM MFMA-bound (LDS 1540 cyc <
//   MFMA 2215 cyc per CU window); residual stall = single-buffer vmcnt(0)
//   drain per K-tile + GEMM3's 1-block/CU (no partner overlap). Fix: BK=128
//   double-buffer (64 KB LDS, still 2 blocks/CU), raw s_barrier, steady-state
//   s_waitcnt vmcnt(8) — tile t+1's 8 loads stay in flight across both
//   barriers while tile t's 32 MFMAs run. (T3/T4; R13's failure was applying
//   this in the LDS-BW-bound regime — regime gate, §5.5.)
//   Stage 1: prep — W1..W3 f32->fp4 W^T (pre-scaled 2^7) + gather (embed fp8,
//            lin, FM partials) + zero mlp-dot accumulator   [one kernel]
//   Stage 2: GEMM1, GEMM2 (A=fp8 acts, B=fp4 weights, 16x16x128 f8f6f4)
//   Stage 3: GEMM3 with fused L4 dot (atomicAdd per sample; H3 never exists)
//   Stage 4: final — redundant-per-block S reduce + sigmoid.  5 nodes.
//
// Swizzle derivation (BK=128, A rows 128 B / 8 chunks, B rows 64 B / 4):
//   A: phys_chunk = logical ^ (row&7); row&7 == ml&7 on read -> full-wave
//      b128 read = 8 word-accesses/bank uniform (conflict-free minimum).
//   B: phys_chunk = logical ^ ((row>>1)&3); same uniformity.
//   global_load_lds dest stays linear (wave-uniform base + lane*16); swizzle
//   realized by permuting per-lane GLOBAL source chunk (m173 pattern).
// ---------------------------------------------------------------------------

typedef float f32x4 __attribute__((ext_vector_type(4)));
typedef int i32x4 __attribute__((ext_vector_type(4)));
typedef int i32x8 __attribute__((ext_vector_type(8)));

#define GLOAD16(gptr, lptr)                                                \
  __builtin_amdgcn_global_load_lds(                                        \
      (const __attribute__((address_space(1))) void*)(gptr),               \
      (__attribute__((address_space(3))) void*)(lptr), 16, 0, 0)

#define BARRIER() asm volatile("s_barrier" ::: "memory")
#define WAITVM(n) asm volatile("s_waitcnt vmcnt(" #n ")" ::: "memory")

// fp4 e2m1 encode (weights only; RNE; magnitudes 0,.5,1,1.5,2,3,4,6)
__device__ inline uint32_t f2fp4(float v) {
  uint32_t s = (__float_as_uint(v) >> 31) << 3;
  float a = fabsf(v);
  uint32_t m;
  if (a < 0.25f) m = 0;
  else if (a < 0.75f) m = 1;
  else if (a < 1.25f) m = 2;
  else if (a < 1.75f) m = 3;
  else if (a < 2.5f)  m = 4;
  else if (a < 3.5f)  m = 5;
  else if (a < 5.0f)  m = 6;
  else m = 7;
  return s | m;
}

// ---------------- workspace layout (bytes) ---------------------------------
static constexpr size_t OFF_LIN  = 0;                          // 16384 f32
static constexpr size_t OFF_PART = 65536;                      // 4096 f32
static constexpr size_t OFF_ACC  = 98304;                      // 16384 f32
static constexpr size_t OFF_EMB  = 262144;                     // B*512 fp8
static constexpr size_t OFF_H1   = OFF_EMB + 8388608ull;       // B*2048 fp8
static constexpr size_t OFF_H2   = OFF_H1 + 33554432ull;       // B*1024 fp8
static constexpr size_t OFF_W1T  = OFF_H2 + 16777216ull;       // 2048*512 fp4
static constexpr size_t OFF_W2T  = OFF_W1T + 524288ull;        // 1024*2048 fp4
static constexpr size_t OFF_W3T  = OFF_W2T + 1048576ull;       // 512*1024 fp4

// ---------------- Stage 1: fused prep (transpose + gather + zero) ----------
__global__ void prep(const float* __restrict__ W1, const float* __restrict__ W2,
                     const float* __restrict__ W3, uint8_t* __restrict__ W1T,
                     uint8_t* __restrict__ W2T, uint8_t* __restrict__ W3T,
                     const float* __restrict__ x, const float* __restrict__ fc,
                     const float* __restrict__ emb, uint8_t* __restrict__ ebf,
                     float* __restrict__ lin, float* __restrict__ partials,
                     float* __restrict__ dotacc) {
  __shared__ __align__(16) float smem[32 * 33];
  int blk = blockIdx.x;
  int tid = threadIdx.x;
  if (blk < 3584) {  // ---- transpose ----
    const float* W;
    uint8_t* WT;
    int K, N, bx, by;
    if (blk < 1024) {        // W1: K=512, N=2048
      W = W1; WT = W1T; K = 512; N = 2048; bx = blk & 63; by = blk >> 6;
    } else if (blk < 3072) { // W2: K=2048, N=1024
      int t = blk - 1024;
      W = W2; WT = W2T; K = 2048; N = 1024; bx = t & 31; by = t >> 5;
    } else {                 // W3: K=1024, N=512
      int t = blk - 3072;
      W = W3; WT = W3T; K = 1024; N = 512; bx = t & 15; by = t >> 4;
    }
    int tx = tid & 31, ty = tid >> 5;
    int n0 = bx * 32, k0 = by * 32;
#pragma unroll
    for (int i = ty; i < 32; i += 8)
      smem[i * 33 + tx] = W[(size_t)(k0 + i) * N + n0 + tx];
    __syncthreads();
    if (tx < 16) {
#pragma unroll
      for (int i = ty; i < 32; i += 8) {
        uint32_t lo = f2fp4(smem[(2 * tx) * 33 + i] * 128.f);
        uint32_t hi = f2fp4(smem[(2 * tx + 1) * 33 + i] * 128.f);
        WT[(size_t)(n0 + i) * (K >> 1) + (k0 >> 1) + tx] =
            (uint8_t)(lo | (hi << 4));
      }
    }
  } else if (blk < 7680) {  // ---- gather ----
    int gb = blk - 3584;
    int wv = tid >> 6, lane = tid & 63;
    int b = gb * 4 + wv;
    int f = lane >> 4;
    int idx = (int)x[b * 4 + f];               // raw index (NO offset) for emb
    const float* row = emb + (size_t)idx * 128 + (lane & 15) * 8;
    float4 v0 = ((const float4*)row)[0];
    float4 v1 = ((const float4*)row)[1];
    float s = v0.x + v0.y + v0.z + v0.w + v1.x + v1.y + v1.z + v1.w;
    float q = v0.x * v0.x + v0.y * v0.y + v0.z * v0.z + v0.w * v0.w +
              v1.x * v1.x + v1.y * v1.y + v1.z * v1.z + v1.w * v1.w;

    int lo = 0, hi = 0;
    lo = __builtin_amdgcn_cvt_pk_fp8_f32(v0.x, v0.y, lo, false);
    lo = __builtin_amdgcn_cvt_pk_fp8_f32(v0.z, v0.w, lo, true);
    hi = __builtin_amdgcn_cvt_pk_fp8_f32(v1.x, v1.y, hi, false);
    hi = __builtin_amdgcn_cvt_pk_fp8_f32(v1.z, v1.w, hi, true);
    int2 pk = make_int2(lo, hi);
    *(int2*)(ebf + (size_t)b * 512 + lane * 8) = pk;   // 8 B/lane coalesced

    float lp = 0.f;
    if ((lane & 15) == 0) {                    // fc lookup USES offsets
      int off = (f == 1) ? 31360 : (f == 2) ? 38167 : (f == 3) ? 38185 : 0;
      lp = fc[idx + off];
    }
#pragma unroll
    for (int m = 32; m; m >>= 1) {
      s += __shfl_xor(s, m);
      q += __shfl_xor(q, m);
      lp += __shfl_xor(lp, m);
    }
    float* pt = smem;
    if (lane == 0) {
      lin[b] = lp;
      pt[wv] = s * s - q;                      // per-sample FM term
    }
    __syncthreads();
    if (tid == 0) partials[gb] = pt[0] + pt[1] + pt[2] + pt[3];
  } else {  // ---- zero mlp-dot accumulator (16 blocks) ----
    int zb = blk - 7680;
    ((float4*)dotacc)[zb * 256 + tid] = make_float4(0.f, 0.f, 0.f, 0.f);
  }
}

// ---------------- Stage 2: mixed GEMM, C = relu(A*B + bias) ----------------
// A fp8 (stride K B), BT fp4 (stride K/2 B), C fp8 (stride N B).
// 128x256 tile, BK=128, double-buffered (2x32 KB LDS, 2 blocks/CU).
// 4 waves in 2x2 grid; per-wave 64x128 output = 4x8 16x16 frags.
// Loop: stage(t+1) -> vmcnt(8) -> barrier -> ds_read + 32 MFMA -> barrier.
// Tile t+1's 8 loads/thread stay in flight across both barriers.
__global__ __launch_bounds__(256, 2) void gemm_mx_relu(
    const uint8_t* __restrict__ A, const uint8_t* __restrict__ BT,
    const float* __restrict__ bias, uint8_t* __restrict__ C, int K, int N,
    int GX) {
  __shared__ __align__(16) uint8_t As[2][128][128];   // 2 x 16 KB
  __shared__ __align__(16) uint8_t Bs[2][256][64];    // 2 x 16 KB
  int bid = blockIdx.x;
  int by = (bid & 7) + ((bid >> 3) / GX) * 8;
  int bx = (bid >> 3) & (GX - 1);
  int tid = threadIdx.x;
  int wv = tid >> 6, lane = tid & 63;
  int m0 = by * 128, n0 = bx * 256;
  int mw = (wv >> 1) * 64, nw = (wv & 1) * 128;
  int ml = lane & 15, kg = lane >> 4;
  int Kb2 = K >> 1;

  // staging lane geometry (swizzle via global source chunk, LDS dest linear)
  int arow = lane >> 3;                          // 0..7 within 8-row group
  int acol = ((lane & 7) ^ arow) * 16;           // logical A chunk bytes
  int brow = lane >> 2;                          // 0..15 within 16-row group
  int bcol = ((lane & 3) ^ ((lane >> 3) & 3)) * 16;  // logical B chunk bytes

  f32x4 acc[4][8];
#pragma unroll
  for (int i = 0; i < 4; ++i)
#pragma unroll
    for (int j = 0; j < 8; ++j) acc[i][j] = (f32x4){0.f, 0.f, 0.f, 0.f};

  int ntile = K >> 7;

  auto stage = [&](int buf, int kt) {
#pragma unroll
    for (int r = 0; r < 4; ++r) {                // A: 16 groups of 8 rows
      int g = r * 4 + wv;
      const uint8_t* ga = A + (size_t)(m0 + 8 * g + arow) * K + kt + acol;
      GLOAD16(ga, &As[buf][8 * g][0]);
    }
#pragma unroll
    for (int r = 0; r < 4; ++r) {                // B: 16 groups of 16 rows
      int g = r * 4 + wv;
      const uint8_t* gb =
          BT + (size_t)(n0 + 16 * g + brow) * Kb2 + (kt >> 1) + bcol;
      GLOAD16(gb, &Bs[buf][16 * g][0]);
    }
  };

  // read-side swizzled offsets (constant per thread)
  int pa0 = ((2 * kg) ^ (ml & 7)) * 16;
  int pa1 = ((2 * kg + 1) ^ (ml & 7)) * 16;
  int pb = (kg ^ ((ml >> 1) & 3)) * 16;

  stage(0, 0);
  int p = 0;
  for (int t = 0; t < ntile; ++t) {
    if (t + 1 < ntile) {
      stage(p ^ 1, (t + 1) << 7);
      WAITVM(8);                                 // tile t's 8 loads done
    } else {
      WAITVM(0);
    }
    BARRIER();

    i32x4 z = (i32x4){0, 0, 0, 0};
    i32x8 af[4];
#pragma unroll
    for (int mt = 0; mt < 4; ++mt) {
      int ra = mw + mt * 16 + ml;
      i32x4 a0 = *(const i32x4*)&As[p][ra][pa0];
      i32x4 a1 = *(const i32x4*)&As[p][ra][pa1];
      af[mt] = __builtin_shufflevector(a0, a1, 0, 1, 2, 3, 4, 5, 6, 7);
    }
    __builtin_amdgcn_s_setprio(1);
#pragma unroll
    for (int nt = 0; nt < 8; ++nt) {
      i32x4 vb = *(const i32x4*)&Bs[p][nw + nt * 16 + ml][pb];
      i32x8 bf = __builtin_shufflevector(vb, z, 0, 1, 2, 3, 4, 5, 6, 7);
#pragma unroll
      for (int mt = 0; mt < 4; ++mt)
        acc[mt][nt] = __builtin_amdgcn_mfma_scale_f32_16x16x128_f8f6f4(
            af[mt], bf, acc[mt][nt],
            /*cbsz=fp8*/ 0, /*blgp=fp4*/ 4,
            0, 0x7F7F7F7F, 0, 0x78787878);
    }
    __builtin_amdgcn_s_setprio(0);
    BARRIER();                                   // all reads of buf p done
    p ^= 1;
  }

  // Epilogue: C/D layout col=lane&15, row=(lane>>4)*4+reg.
  int rbase = kg * 4;
#pragma unroll
  for (int nt = 0; nt < 8; ++nt) {
    int col = n0 + nw + nt * 16 + ml;
    float bv = bias[col];
#pragma unroll
    for (int mt = 0; mt < 4; ++mt) {
      int row = m0 + mw + mt * 16 + rbase;
      float v0 = acc[mt][nt][0] + bv, v1 = acc[mt][nt][1] + bv;
      float v2 = acc[mt][nt][2] + bv, v3 = acc[mt][nt][3] + bv;
      v0 = v0 > 0.f ? v0 : 0.f;
      v1 = v1 > 0.f ? v1 : 0.f;
      v2 = v2 > 0.f ? v2 : 0.f;
      v3 = v3 > 0.f ? v3 : 0.f;
      int w01 = __builtin_amdgcn_cvt_pk_fp8_f32(v0, v1, 0, false);
      int w23 = __builtin_amdgcn_cvt_pk_fp8_f32(v2, v3, 0, false);
      C[(size_t)(row + 0) * N + col] = (uint8_t)(w01 & 0xFF);
      C[(size_t)(row + 1) * N + col] = (uint8_t)((w01 >> 8) & 0xFF);
      C[(size_t)(row + 2) * N + col] = (uint8_t)(w23 & 0xFF);
      C[(size_t)(row + 3) * N + col] = (uint8_t)((w23 >> 8) & 0xFF);
    }
  }
}

// ---------------- Stage 3: GEMM3 + fused L4 partial dot --------------------
__global__ __launch_bounds__(256, 2) void gemm_mx_dot(
    const uint8_t* __restrict__ A, const uint8_t* __restrict__ BT,
    const float* __restrict__ bias, const float* __restrict__ W4,
    float* __restrict__ dotacc, int K, int N, int GX) {
  __shared__ __align__(16) uint8_t As[2][128][128];
  __shared__ __align__(16) uint8_t Bs[2][256][64];
  int bid = blockIdx.x;
  int by = (bid & 7) + ((bid >> 3) / GX) * 8;
  int bx = (bid >> 3) & (GX - 1);
  int tid = threadIdx.x;
  int wv = tid >> 6, lane = tid & 63;
  int m0 = by * 128, n0 = bx * 256;
  int mw = (wv >> 1) * 64, nw = (wv & 1) * 128;
  int ml = lane & 15, kg = lane >> 4;
  int Kb2 = K >> 1;

  int arow = lane >> 3;
  int acol = ((lane & 7) ^ arow) * 16;
  int brow = lane >> 2;
  int bcol = ((lane & 3) ^ ((lane >> 3) & 3)) * 16;

  f32x4 acc[4][8];
#pragma unroll
  for (int i = 0; i < 4; ++i)
#pragma unroll
    for (int j = 0; j < 8; ++j) acc[i][j] = (f32x4){0.f, 0.f, 0.f, 0.f};

  int ntile = K >> 7;

  auto stage = [&](int buf, int kt) {
#pragma unroll
    for (int r = 0; r < 4; ++r) {
      int g = r * 4 + wv;
      const uint8_t* ga = A + (size_t)(m0 + 8 * g + arow) * K + kt + acol;
      GLOAD16(ga, &As[buf][8 * g][0]);
    }
#pragma unroll
    for (int r = 0; r < 4; ++r) {
      int g = r * 4 + wv;
      const uint8_t* gb =
          BT + (size_t)(n0 + 16 * g + brow) * Kb2 + (kt >> 1) + bcol;
      GLOAD16(gb, &Bs[buf][16 * g][0]);
    }
  };

  int pa0 = ((2 * kg) ^ (ml & 7)) * 16;
  int pa1 = ((2 * kg + 1) ^ (ml & 7)) * 16;
  int pb = (kg ^ ((ml >> 1) & 3)) * 16;

  stage(0, 0);
  int p = 0;
  for (int t = 0; t < ntile; ++t) {
    if (t + 1 < ntile) {
      stage(p ^ 1, (t + 1) << 7);
      WAITVM(8);
    } else {
      WAITVM(0);
    }
    BARRIER();

    i32x4 z = (i32x4){0, 0, 0, 0};
    i32x8 af[4];
#pragma unroll
    for (int mt = 0; mt < 4; ++mt) {
      int ra = mw + mt * 16 + ml;
      i32x4 a0 = *(const i32x4*)&As[p][ra][pa0];
      i32x4 a1 = *(const i32x4*)&As[p][ra][pa1];
      af[mt] = __builtin_shufflevector(a0, a1, 0, 1, 2, 3, 4, 5, 6, 7);
    }
    __builtin_amdgcn_s_setprio(1);
#pragma unroll
    for (int nt = 0; nt < 8; ++nt) {
      i32x4 vb = *(const i32x4*)&Bs[p][nw + nt * 16 + ml][pb];
      i32x8 bf = __builtin_shufflevector(vb, z, 0, 1, 2, 3, 4, 5, 6, 7);
#pragma unroll
      for (int mt = 0; mt < 4; ++mt)
        acc[mt][nt] = __builtin_amdgcn_mfma_scale_f32_16x16x128_f8f6f4(
            af[mt], bf, acc[mt][nt],
            0, 4, 0, 0x7F7F7F7F, 0, 0x78787878);
    }
    __builtin_amdgcn_s_setprio(0);
    BARRIER();
    p ^= 1;
  }

  // Fused epilogue: h = relu(acc + b3[col]); p[row] += h * W4[col];
  // shfl-reduce over the 16 lanes sharing each row; lane 0 atomicAdds.
  float bv[8], w4v[8];
#pragma unroll
  for (int nt = 0; nt < 8; ++nt) {
    int col = n0 + nw + nt * 16 + ml;
    bv[nt] = bias[col];
    w4v[nt] = W4[col];
  }
  int rbase = kg * 4;
#pragma unroll
  for (int mt = 0; mt < 4; ++mt) {
#pragma unroll
    for (int r = 0; r < 4; ++r) {
      float pacc = 0.f;
#pragma unroll
      for (int nt = 0; nt < 8; ++nt) {
        float v = acc[mt][nt][r] + bv[nt];
        v = v > 0.f ? v : 0.f;
        pacc += v * w4v[nt];
      }
#pragma unroll
      for (int m = 1; m < 16; m <<= 1) pacc += __shfl_xor(pacc, m);
      if (ml == 0)
        atomicAdd(&dotacc[m0 + mw + mt * 16 + rbase + r], pacc);
    }
  }
}

// ---------------- Stage 4: final — S reduce + sigmoid ----------------------
__global__ void final_out(const float* __restrict__ part,
                          const float* __restrict__ dotacc,
                          const float* __restrict__ lin,
                          const float* __restrict__ bias,
                          const float* __restrict__ b4,
                          float* __restrict__ out) {
  __shared__ float ps[4];
  int tid = threadIdx.x;
  float v = 0.f;
  for (int i = tid; i < 4096; i += 256) v += part[i];
#pragma unroll
  for (int m = 32; m; m >>= 1) v += __shfl_xor(v, m);
  if ((tid & 63) == 0) ps[tid >> 6] = v;
  __syncthreads();
  float S = ps[0] + ps[1] + ps[2] + ps[3];
  int i = blockIdx.x * 256 + tid;
  float z = dotacc[i] + b4[0] + bias[0] + lin[i] + 0.5f * S;
  out[i] = 1.f / (1.f + expf(-z));
}

// ---------------------------------------------------------------------------
extern "C" void kernel_launch(void* const* d_in, const int* in_sizes, int n_in,
                              void* d_out, int out_size, void* d_ws,
                              size_t ws_size, hipStream_t stream) {
  const float* x    = (const float*)d_in[0];
  const float* bias = (const float*)d_in[1];
  const float* fc   = (const float*)d_in[2];
  const float* emb  = (const float*)d_in[3];
  const float* W1   = (const float*)d_in[4];
  const float* b1   = (const float*)d_in[5];
  const float* W2   = (const float*)d_in[6];
  const float* b2   = (const float*)d_in[7];
  const float* W3   = (const float*)d_in[8];
  const float* b3   = (const float*)d_in[9];
  const float* W4   = (const float*)d_in[10];
  const float* b4   = (const float*)d_in[11];
  float* out = (float*)d_out;

  char* ws = (char*)d_ws;
  float* lin    = (float*)(ws + OFF_LIN);
  float* part   = (float*)(ws + OFF_PART);
  float* dacc   = (float*)(ws + OFF_ACC);
  uint8_t* EMBb = (uint8_t*)(ws + OFF_EMB);
  uint8_t* H1   = (uint8_t*)(ws + OFF_H1);
  uint8_t* H2   = (uint8_t*)(ws + OFF_H2);
  uint8_t* W1T  = (uint8_t*)(ws + OFF_W1T);
  uint8_t* W2T  = (uint8_t*)(ws + OFF_W2T);
  uint8_t* W3T  = (uint8_t*)(ws + OFF_W3T);

  prep<<<7696, 256, 0, stream>>>(W1, W2, W3, W1T, W2T, W3T, x, fc, emb, EMBb,
                                 lin, part, dacc);

  // 128x256 tiles: grid = 128 * (N/256)
  gemm_mx_relu<<<1024, 256, 0, stream>>>(EMBb, W1T, b1, H1, 512, 2048, 8);
  gemm_mx_relu<<<512, 256, 0, stream>>>(H1, W2T, b2, H2, 2048, 1024, 4);
  gemm_mx_dot<<<256, 256, 0, stream>>>(H2, W3T, b3, W4, dacc, 1024, 512, 2);

  final_out<<<64, 256, 0, stream>>>(part, dacc, lin, bias, b4, out);
}

// Round 4
// 163.938 us; speedup vs baseline: 1.0854x; 1.0854x over previous
//
#include <hip/hip_runtime.h>
#include <hip/hip_fp8.h>
#include <cstdint>

// ---------------------------------------------------------------------------
// DeepFM forward, MI355X (R16 = fp4 activations for GEMM2/GEMM3).
//   R13/R15 post-mortem: counted-vmcnt pipelining neutral/regressive twice ->
//   scheduling exhausted; R14 (128x256 tile, BK=256, single-buffer) is the
//   structural optimum. Remaining lever = MFMA RATE: fp8xfp4 issues at the
//   fp8 rate; fp4xfp4 at 2x. Quantize H1/H2 to fp4 (86/120 GFLOP at 2x).
//   K-permutation trick: fp4 bytes hold col-pairs (32p+i, 32p+i+16) so the
//   GEMM epilogue packs lane-locally (no shuffles); W2T/W3T packed in the
//   SAME permuted pair order (MFMA dot is K-permutation invariant).
//   Scales: H1 stored x2 (scale_a 2^-1=0x7E), H2 stored x4 (2^-2=0x7D),
//   weights x128 (2^-7=0x78). FM path stays exact f32 (dominates z).
//   Stage 1: prep — W^T fp4 (W1 natural pairs, W2/W3 permuted pairs) +
//            gather (embed fp8, lin, FM partials) + zero dotacc
//   Stage 2: GEMM1 (A fp8 x B fp4 -> H1 fp4), GEMM2 (fp4 x fp4 -> H2 fp4)
//   Stage 3: GEMM3 (fp4 x fp4) with fused L4 dot (atomicAdd per sample)
//   Stage 4: final — redundant-per-block S reduce + sigmoid.  5 nodes.
// ---------------------------------------------------------------------------

typedef float f32x4 __attribute__((ext_vector_type(4)));
typedef int i32x4 __attribute__((ext_vector_type(4)));
typedef int i32x8 __attribute__((ext_vector_type(8)));

#define GLOAD16(gptr, lptr)                                                \
  __builtin_amdgcn_global_load_lds(                                        \
      (const __attribute__((address_space(1))) void*)(gptr),               \
      (__attribute__((address_space(3))) void*)(lptr), 16, 0, 0)

// fp4 e2m1 encode (weights; signed; RNE; magnitudes 0,.5,1,1.5,2,3,4,6)
__device__ inline uint32_t f2fp4(float v) {
  uint32_t s = (__float_as_uint(v) >> 31) << 3;
  float a = fabsf(v);
  uint32_t m;
  if (a < 0.25f) m = 0;
  else if (a < 0.75f) m = 1;
  else if (a < 1.25f) m = 2;
  else if (a < 1.75f) m = 3;
  else if (a < 2.5f)  m = 4;
  else if (a < 3.5f)  m = 5;
  else if (a < 5.0f)  m = 6;
  else m = 7;
  return s | m;
}

// fp4 e2m1 encode, non-negative input (post-relu), branchless RNE bit-trick.
// codes: 0->0, 1->0.5, 2->1, 3->1.5, 4->2, 5->3, 6->4, 7->6.
__device__ inline uint32_t enc4(float x) {
  float c = fminf(fmaxf(x, 0.5f), 6.0f);
  uint32_t u = __float_as_uint(c);
  u += 0x001FFFFFu + ((u >> 22) & 1u);      // RNE at mantissa bit 22
  int code = (int)(u >> 22) - 252;          // 2E+m -> code (>=1.0 region)
  code = code < 1 ? 1 : code;               // [0.5,1) region -> code 1
  return x < 0.25f ? 0u : (uint32_t)code;
}

// ---------------- workspace layout (bytes) ---------------------------------
static constexpr size_t OFF_LIN  = 0;                          // 16384 f32
static constexpr size_t OFF_PART = 65536;                      // 4096 f32
static constexpr size_t OFF_ACC  = 98304;                      // 16384 f32
static constexpr size_t OFF_EMB  = 262144;                     // B*512 fp8
static constexpr size_t OFF_H1   = OFF_EMB + 8388608ull;       // B*1024 fp4
static constexpr size_t OFF_H2   = OFF_H1 + 33554432ull;       // B*512  fp4
static constexpr size_t OFF_W1T  = OFF_H2 + 16777216ull;       // 2048*512 fp4
static constexpr size_t OFF_W2T  = OFF_W1T + 524288ull;        // 1024*2048 fp4
static constexpr size_t OFF_W3T  = OFF_W2T + 1048576ull;       // 512*1024 fp4

// ---------------- Stage 1: fused prep (transpose + gather + zero) ----------
__global__ void prep(const float* __restrict__ W1, const float* __restrict__ W2,
                     const float* __restrict__ W3, uint8_t* __restrict__ W1T,
                     uint8_t* __restrict__ W2T, uint8_t* __restrict__ W3T,
                     const float* __restrict__ x, const float* __restrict__ fc,
                     const float* __restrict__ emb, uint8_t* __restrict__ ebf,
                     float* __restrict__ lin, float* __restrict__ partials,
                     float* __restrict__ dotacc) {
  __shared__ __align__(16) float smem[32 * 33];
  int blk = blockIdx.x;
  int tid = threadIdx.x;
  if (blk < 3584) {  // ---- transpose ----
    const float* W;
    uint8_t* WT;
    int K, N, bx, by;
    bool perm;                // permuted K-pairs (tx, tx+16) for W2/W3
    if (blk < 1024) {        // W1: K=512, N=2048 (natural pairs: GEMM1 A=fp8)
      W = W1; WT = W1T; K = 512; N = 2048; bx = blk & 63; by = blk >> 6;
      perm = false;
    } else if (blk < 3072) { // W2: K=2048, N=1024
      int t = blk - 1024;
      W = W2; WT = W2T; K = 2048; N = 1024; bx = t & 31; by = t >> 5;
      perm = true;
    } else {                 // W3: K=1024, N=512
      int t = blk - 3072;
      W = W3; WT = W3T; K = 1024; N = 512; bx = t & 15; by = t >> 4;
      perm = true;
    }
    int tx = tid & 31, ty = tid >> 5;
    int n0 = bx * 32, k0 = by * 32;
#pragma unroll
    for (int i = ty; i < 32; i += 8)
      smem[i * 33 + tx] = W[(size_t)(k0 + i) * N + n0 + tx];
    __syncthreads();
    if (tx < 16) {
      int kA = perm ? tx : 2 * tx;        // low-nibble k within 32-block
      int kB = perm ? tx + 16 : 2 * tx + 1;
#pragma unroll
      for (int i = ty; i < 32; i += 8) {
        uint32_t lo = f2fp4(smem[kA * 33 + i] * 128.f);
        uint32_t hi = f2fp4(smem[kB * 33 + i] * 128.f);
        WT[(size_t)(n0 + i) * (K >> 1) + (k0 >> 1) + tx] =
            (uint8_t)(lo | (hi << 4));
      }
    }
  } else if (blk < 7680) {  // ---- gather ----
    int gb = blk - 3584;
    int wv = tid >> 6, lane = tid & 63;
    int b = gb * 4 + wv;
    int f = lane >> 4;
    int idx = (int)x[b * 4 + f];               // raw index (NO offset) for emb
    const float* row = emb + (size_t)idx * 128 + (lane & 15) * 8;
    float4 v0 = ((const float4*)row)[0];
    float4 v1 = ((const float4*)row)[1];
    float s = v0.x + v0.y + v0.z + v0.w + v1.x + v1.y + v1.z + v1.w;
    float q = v0.x * v0.x + v0.y * v0.y + v0.z * v0.z + v0.w * v0.w +
              v1.x * v1.x + v1.y * v1.y + v1.z * v1.z + v1.w * v1.w;

    int lo = 0, hi = 0;
    lo = __builtin_amdgcn_cvt_pk_fp8_f32(v0.x, v0.y, lo, false);
    lo = __builtin_amdgcn_cvt_pk_fp8_f32(v0.z, v0.w, lo, true);
    hi = __builtin_amdgcn_cvt_pk_fp8_f32(v1.x, v1.y, hi, false);
    hi = __builtin_amdgcn_cvt_pk_fp8_f32(v1.z, v1.w, hi, true);
    int2 pk = make_int2(lo, hi);
    *(int2*)(ebf + (size_t)b * 512 + lane * 8) = pk;   // 8 B/lane coalesced

    float lp = 0.f;
    if ((lane & 15) == 0) {                    // fc lookup USES offsets
      int off = (f == 1) ? 31360 : (f == 2) ? 38167 : (f == 3) ? 38185 : 0;
      lp = fc[idx + off];
    }
#pragma unroll
    for (int m = 32; m; m >>= 1) {
      s += __shfl_xor(s, m);
      q += __shfl_xor(q, m);
      lp += __shfl_xor(lp, m);
    }
    float* pt = smem;
    if (lane == 0) {
      lin[b] = lp;
      pt[wv] = s * s - q;                      // per-sample FM term
    }
    __syncthreads();
    if (tid == 0) partials[gb] = pt[0] + pt[1] + pt[2] + pt[3];
  } else {  // ---- zero mlp-dot accumulator (16 blocks) ----
    int zb = blk - 7680;
    ((float4*)dotacc)[zb * 256 + tid] = make_float4(0.f, 0.f, 0.f, 0.f);
  }
}

// ---------------- Stage 2: mixed GEMM, C = fp4(relu(A*B + bias) * osc) -----
// A fp8 (AFP4=false, stride K B) or fp4 (AFP4=true, stride K/2 B);
// BT fp4 (stride K/2 B); C fp4 packed permuted pairs (stride N/2 B).
// 128x256 tile, BK=256, single-buffered (R14 structure, proven best).
// 4 waves 2x2; per-wave 64x128 output = 4x8 16x16 frags.
template <bool AFP4>
__global__ __launch_bounds__(256, 2) void gemm_mx_q4(
    const uint8_t* __restrict__ A, const uint8_t* __restrict__ BT,
    const float* __restrict__ bias, uint8_t* __restrict__ C, int K, int N,
    int GX, int sa, float osc) {
  constexpr int ABYTES = AFP4 ? 128 : 256;          // A tile-row bytes
  __shared__ __align__(16) uint8_t As[128][ABYTES]; // 16/32 KB
  __shared__ __align__(16) uint8_t Bs[256][128];    // 32 KB
  int bid = blockIdx.x;
  int by = (bid & 7) + ((bid >> 3) / GX) * 8;
  int bx = (bid >> 3) & (GX - 1);
  int tid = threadIdx.x;
  int wv = tid >> 6, lane = tid & 63;
  int m0 = by * 128, n0 = bx * 256;
  int mw = (wv >> 1) * 64, nw = (wv & 1) * 128;
  int ml = lane & 15, kg = lane >> 4;
  int Kb2 = K >> 1;

  // staging lane geometry (swizzle via global source chunk, LDS dest linear)
  int arow16 = wv * 4 + (lane >> 4);             // fp8 A: 16-row groups
  int acol16 = ((lane & 15) ^ arow16) * 16;
  int arow8 = lane >> 3;                         // fp4 A: 8-row groups
  int acol8 = ((lane & 7) ^ arow8) * 16;
  int brow = wv * 8 + (lane >> 3);               // B: 32-row groups
  int bcol = ((lane & 7) ^ (brow & 7)) * 16;

  f32x4 acc[4][8];
#pragma unroll
  for (int i = 0; i < 4; ++i)
#pragma unroll
    for (int j = 0; j < 8; ++j) acc[i][j] = (f32x4){0.f, 0.f, 0.f, 0.f};

  for (int kt = 0; kt < K; kt += 256) {
    if constexpr (!AFP4) {
#pragma unroll
      for (int r = 0; r < 8; ++r) {              // A fp8: 8 groups of 16 rows
        const uint8_t* ga = A + (size_t)(m0 + r * 16 + arow16) * K + kt + acol16;
        GLOAD16(ga, &As[r * 16 + wv * 4][0]);
      }
    } else {
#pragma unroll
      for (int r = 0; r < 4; ++r) {              // A fp4: 16 groups of 8 rows
        int g = r * 4 + wv;
        const uint8_t* ga =
            A + (size_t)(m0 + 8 * g + arow8) * Kb2 + (kt >> 1) + acol8;
        GLOAD16(ga, &As[8 * g][0]);
      }
    }
#pragma unroll
    for (int r = 0; r < 8; ++r) {                // B: 8 groups of 32 rows
      const uint8_t* gb =
          BT + (size_t)(n0 + r * 32 + brow) * Kb2 + (kt >> 1) + bcol;
      GLOAD16(gb, &Bs[r * 32 + wv * 8][0]);
    }
    __syncthreads();

    i32x4 z = (i32x4){0, 0, 0, 0};
#pragma unroll
    for (int j = 0; j < 2; ++j) {                // two 128-elem k-halves
      int pb = ((4 * j + kg) ^ (ml & 7)) * 16;
      i32x8 af[4];
#pragma unroll
      for (int mt = 0; mt < 4; ++mt) {
        int ra = mw + mt * 16 + ml;
        if constexpr (!AFP4) {
          int pa0 = ((8 * j + 2 * kg) ^ ml) * 16;
          int pa1 = ((8 * j + 2 * kg + 1) ^ ml) * 16;
          i32x4 a0 = *(const i32x4*)&As[ra][pa0];
          i32x4 a1 = *(const i32x4*)&As[ra][pa1];
          af[mt] = __builtin_shufflevector(a0, a1, 0, 1, 2, 3, 4, 5, 6, 7);
        } else {
          int pa = ((4 * j + kg) ^ (ml & 7)) * 16;
          i32x4 a0 = *(const i32x4*)&As[ra][pa];
          af[mt] = __builtin_shufflevector(a0, z, 0, 1, 2, 3, 4, 5, 6, 7);
        }
      }
#pragma unroll
      for (int nt = 0; nt < 8; ++nt) {
        i32x4 vb = *(const i32x4*)&Bs[nw + nt * 16 + ml][pb];
        i32x8 bf = __builtin_shufflevector(vb, z, 0, 1, 2, 3, 4, 5, 6, 7);
#pragma unroll
        for (int mt = 0; mt < 4; ++mt)
          acc[mt][nt] = __builtin_amdgcn_mfma_scale_f32_16x16x128_f8f6f4(
              af[mt], bf, acc[mt][nt],
              /*cbsz*/ AFP4 ? 4 : 0, /*blgp=fp4*/ 4,
              0, sa, 0, 0x78787878);
      }
    }
    __syncthreads();
  }

  // Epilogue: C/D layout col=lane&15, row=(lane>>4)*4+reg.
  // fp4 pack, permuted pairs: byte (16p + ml) of each 64-byte half holds
  // cols (n0+nw+32p+ml) low nibble, (+16) high nibble.
  int rbase = kg * 4;
  int NB = N >> 1;
  int cb0 = ((n0 + nw) >> 1) + ml;
  float bvo[8];
#pragma unroll
  for (int nt = 0; nt < 8; ++nt) bvo[nt] = bias[n0 + nw + nt * 16 + ml] * osc;
#pragma unroll
  for (int mt = 0; mt < 4; ++mt) {
    int row = m0 + mw + mt * 16 + rbase;
#pragma unroll
    for (int p = 0; p < 4; ++p) {
#pragma unroll
      for (int r = 0; r < 4; ++r) {
        float xl = fmaxf(fmaf(acc[mt][2 * p][r], osc, bvo[2 * p]), 0.f);
        float xh = fmaxf(fmaf(acc[mt][2 * p + 1][r], osc, bvo[2 * p + 1]), 0.f);
        C[(size_t)(row + r) * NB + cb0 + p * 16] =
            (uint8_t)(enc4(xl) | (enc4(xh) << 4));
      }
    }
  }
}

// ---------------- Stage 3: GEMM3 (fp4 x fp4) + fused L4 partial dot --------
__global__ __launch_bounds__(256, 2) void gemm_mx_dot(
    const uint8_t* __restrict__ A, const uint8_t* __restrict__ BT,
    const float* __restrict__ bias, const float* __restrict__ W4,
    float* __restrict__ dotacc, int K, int N, int GX, int sa) {
  __shared__ __align__(16) uint8_t As[128][128];
  __shared__ __align__(16) uint8_t Bs[256][128];
  int bid = blockIdx.x;
  int by = (bid & 7) + ((bid >> 3) / GX) * 8;
  int bx = (bid >> 3) & (GX - 1);
  int tid = threadIdx.x;
  int wv = tid >> 6, lane = tid & 63;
  int m0 = by * 128, n0 = bx * 256;
  int mw = (wv >> 1) * 64, nw = (wv & 1) * 128;
  int ml = lane & 15, kg = lane >> 4;
  int Kb2 = K >> 1;

  int arow8 = lane >> 3;
  int acol8 = ((lane & 7) ^ arow8) * 16;
  int brow = wv * 8 + (lane >> 3);
  int bcol = ((lane & 7) ^ (brow & 7)) * 16;

  f32x4 acc[4][8];
#pragma unroll
  for (int i = 0; i < 4; ++i)
#pragma unroll
    for (int j = 0; j < 8; ++j) acc[i][j] = (f32x4){0.f, 0.f, 0.f, 0.f};

  for (int kt = 0; kt < K; kt += 256) {
#pragma unroll
    for (int r = 0; r < 4; ++r) {
      int g = r * 4 + wv;
      const uint8_t* ga =
          A + (size_t)(m0 + 8 * g + arow8) * Kb2 + (kt >> 1) + acol8;
      GLOAD16(ga, &As[8 * g][0]);
    }
#pragma unroll
    for (int r = 0; r < 8; ++r) {
      const uint8_t* gb =
          BT + (size_t)(n0 + r * 32 + brow) * Kb2 + (kt >> 1) + bcol;
      GLOAD16(gb, &Bs[r * 32 + wv * 8][0]);
    }
    __syncthreads();

    i32x4 z = (i32x4){0, 0, 0, 0};
#pragma unroll
    for (int j = 0; j < 2; ++j) {
      int pb = ((4 * j + kg) ^ (ml & 7)) * 16;
      i32x8 af[4];
#pragma unroll
      for (int mt = 0; mt < 4; ++mt) {
        int ra = mw + mt * 16 + ml;
        int pa = ((4 * j + kg) ^ (ml & 7)) * 16;
        i32x4 a0 = *(const i32x4*)&As[ra][pa];
        af[mt] = __builtin_shufflevector(a0, z, 0, 1, 2, 3, 4, 5, 6, 7);
      }
#pragma unroll
      for (int nt = 0; nt < 8; ++nt) {
        i32x4 vb = *(const i32x4*)&Bs[nw + nt * 16 + ml][pb];
        i32x8 bf = __builtin_shufflevector(vb, z, 0, 1, 2, 3, 4, 5, 6, 7);
#pragma unroll
        for (int mt = 0; mt < 4; ++mt)
          acc[mt][nt] = __builtin_amdgcn_mfma_scale_f32_16x16x128_f8f6f4(
              af[mt], bf, acc[mt][nt],
              /*cbsz=fp4*/ 4, /*blgp=fp4*/ 4,
              0, sa, 0, 0x78787878);
      }
    }
    __syncthreads();
  }

  // Fused epilogue: h = relu(acc + b3[col]); p[row] += h * W4[col];
  // shfl-reduce over the 16 lanes sharing each row; lane 0 atomicAdds.
  float bv[8], w4v[8];
#pragma unroll
  for (int nt = 0; nt < 8; ++nt) {
    int col = n0 + nw + nt * 16 + ml;
    bv[nt] = bias[col];
    w4v[nt] = W4[col];
  }
  int rbase = kg * 4;
#pragma unroll
  for (int mt = 0; mt < 4; ++mt) {
#pragma unroll
    for (int r = 0; r < 4; ++r) {
      float p = 0.f;
#pragma unroll
      for (int nt = 0; nt < 8; ++nt) {
        float v = acc[mt][nt][r] + bv[nt];
        v = v > 0.f ? v : 0.f;
        p += v * w4v[nt];
      }
#pragma unroll
      for (int m = 1; m < 16; m <<= 1) p += __shfl_xor(p, m);
      if (ml == 0)
        atomicAdd(&dotacc[m0 + mw + mt * 16 + rbase + r], p);
    }
  }
}

// ---------------- Stage 4: final — S reduce + sigmoid ----------------------
__global__ void final_out(const float* __restrict__ part,
                          const float* __restrict__ dotacc,
                          const float* __restrict__ lin,
                          const float* __restrict__ bias,
                          const float* __restrict__ b4,
                          float* __restrict__ out) {
  __shared__ float ps[4];
  int tid = threadIdx.x;
  float v = 0.f;
  for (int i = tid; i < 4096; i += 256) v += part[i];
#pragma unroll
  for (int m = 32; m; m >>= 1) v += __shfl_xor(v, m);
  if ((tid & 63) == 0) ps[tid >> 6] = v;
  __syncthreads();
  float S = ps[0] + ps[1] + ps[2] + ps[3];
  int i = blockIdx.x * 256 + tid;
  float z = dotacc[i] + b4[0] + bias[0] + lin[i] + 0.5f * S;
  out[i] = 1.f / (1.f + expf(-z));
}

// ---------------------------------------------------------------------------
extern "C" void kernel_launch(void* const* d_in, const int* in_sizes, int n_in,
                              void* d_out, int out_size, void* d_ws,
                              size_t ws_size, hipStream_t stream) {
  const float* x    = (const float*)d_in[0];
  const float* bias = (const float*)d_in[1];
  const float* fc   = (const float*)d_in[2];
  const float* emb  = (const float*)d_in[3];
  const float* W1   = (const float*)d_in[4];
  const float* b1   = (const float*)d_in[5];
  const float* W2   = (const float*)d_in[6];
  const float* b2   = (const float*)d_in[7];
  const float* W3   = (const float*)d_in[8];
  const float* b3   = (const float*)d_in[9];
  const float* W4   = (const float*)d_in[10];
  const float* b4   = (const float*)d_in[11];
  float* out = (float*)d_out;

  char* ws = (char*)d_ws;
  float* lin    = (float*)(ws + OFF_LIN);
  float* part   = (float*)(ws + OFF_PART);
  float* dacc   = (float*)(ws + OFF_ACC);
  uint8_t* EMBb = (uint8_t*)(ws + OFF_EMB);
  uint8_t* H1   = (uint8_t*)(ws + OFF_H1);
  uint8_t* H2   = (uint8_t*)(ws + OFF_H2);
  uint8_t* W1T  = (uint8_t*)(ws + OFF_W1T);
  uint8_t* W2T  = (uint8_t*)(ws + OFF_W2T);
  uint8_t* W3T  = (uint8_t*)(ws + OFF_W3T);

  prep<<<7696, 256, 0, stream>>>(W1, W2, W3, W1T, W2T, W3T, x, fc, emb, EMBb,
                                 lin, part, dacc);

  // 128x256 tiles: grid = 128 * (N/256)
  // GEMM1: A fp8 (scale 1.0 = 0x7F), out H1 stored x2
  gemm_mx_q4<false><<<1024, 256, 0, stream>>>(EMBb, W1T, b1, H1, 512, 2048, 8,
                                              0x7F7F7F7F, 2.0f);
  // GEMM2: A fp4 H1 (x2 -> scale 2^-1 = 0x7E), out H2 stored x4
  gemm_mx_q4<true><<<512, 256, 0, stream>>>(H1, W2T, b2, H2, 2048, 1024, 4,
                                            0x7E7E7E7E, 4.0f);
  // GEMM3: A fp4 H2 (x4 -> scale 2^-2 = 0x7D)
  gemm_mx_dot<<<256, 256, 0, stream>>>(H2, W3T, b3, W4, dacc, 1024, 512, 2,
                                       0x7D7D7D7D);

  final_out<<<64, 256, 0, stream>>>(part, dacc, lin, bias, b4, out);
}